// Round 1
// baseline (1432.544 us; speedup 1.0000x reference)
//
#include <hip/hip_runtime.h>
#include <cfloat>

#define ITEMS 64
#define HID   256
#define BLK   512               // 8 waves; each wave owns 64 samples per chunk
#define WROW  68                // fp32 W row stride (272 B, float4-aligned, bank-staggered)
#define HROW  72                // bf16 W row stride (144 B, 16B-aligned, bank-uniform b128)
#define BAND  0.016f            // 2*B ; worst-case |approx-exact| <= 3.9e-3, 2x margin

typedef __attribute__((ext_vector_type(8))) short bf16x8;   // 8 bf16 = 4 VGPRs
typedef __attribute__((ext_vector_type(4))) float f32x4;

#define MFMA(A,B,C) __builtin_amdgcn_mfma_f32_16x16x32_bf16((A),(B),(C),0,0,0)

__global__ __launch_bounds__(BLK, 2) void rochet_fwd(
    const float* __restrict__ val,   // [B, 64]
    const float* __restrict__ W,     // [256, 64]
    const float* __restrict__ w0,    // [256]
    float* __restrict__ alloc,       // [B, 64]
    float* __restrict__ pay,         // [B]
    int batch)
{
    // 36,864 + 36,864 + 69,632 + 16,384 + 1,024 + 2,048 = 162,816 B (<= 160 KiB)
    __shared__ __attribute__((aligned(16))) ushort lWh[HID * HROW];  // bf16 hi(W)
    __shared__ __attribute__((aligned(16))) ushort lWl[HID * HROW];  // bf16 lo(W)
    __shared__ __attribute__((aligned(16))) float  lWf[HID * WROW];  // exact fp32 W
    __shared__ __attribute__((aligned(16))) ushort cmask[BLK * 16];  // per-sample candidate bits
    __shared__ float lw0[HID];
    __shared__ int   stage[BLK];

    const int tid = threadIdx.x;

    // ---- Stage W: fp32 copy + truncation-split bf16 hi/lo; w0 ----
    {
        const int r  = tid >> 1;
        const int hh = (tid & 1) * 32;                 // half-row of 32 floats
        const float4* wg = reinterpret_cast<const float4*>(W + r * ITEMS + hh);
        float4* wf = reinterpret_cast<float4*>(&lWf[r * WROW + hh]);
        uint*   ph = reinterpret_cast<uint*>(&lWh[r * HROW + hh]);
        uint*   pl = reinterpret_cast<uint*>(&lWl[r * HROW + hh]);
        #pragma unroll
        for (int q = 0; q < 8; ++q) {
            float4 w4 = wg[q];
            wf[q] = w4;
            float f[4] = {w4.x, w4.y, w4.z, w4.w};
            #pragma unroll
            for (int p = 0; p < 2; ++p) {
                uint  b0 = __float_as_uint(f[2*p+0]);
                uint  b1 = __float_as_uint(f[2*p+1]);
                float r0 = f[2*p+0] - __uint_as_float(b0 & 0xffff0000u);  // exact
                float r1 = f[2*p+1] - __uint_as_float(b1 & 0xffff0000u);  // exact
                ph[2*q+p] = (b0 >> 16) | (b1 & 0xffff0000u);
                pl[2*q+p] = (__float_as_uint(r0) >> 16) | (__float_as_uint(r1) & 0xffff0000u);
            }
        }
        if (tid < HID) lw0[tid] = w0[tid];
    }
    __syncthreads();
    // Everything below is wave-local: no further barriers.

    const int wave = tid >> 6, lane = tid & 63;
    const int c = lane & 15, g = lane >> 4;            // MFMA lane decomposition
    const int nchunks = (batch + 63) >> 6;             // 64-sample chunks
    const int nw = (gridDim.x * BLK) >> 6;             // total waves (persistent grid)

    for (int ch = blockIdx.x * (BLK >> 6) + wave; ch < nchunks; ch += nw) {
        const int ms = ch << 6;                        // this wave's first sample

        // ---- A fragments: val rows ms+m*16+c, k-block = 8*g (+32), bf16 hi/lo ----
        bf16x8 Ah[4][2], Al[4][2];
        #pragma unroll
        for (int m = 0; m < 4; ++m) {
            int srow = ms + m * 16 + c;
            if (srow >= batch) srow = batch - 1;       // safe duplicate; result unused
            const float4* vp = reinterpret_cast<const float4*>(val + (size_t)srow * ITEMS);
            #pragma unroll
            for (int ko = 0; ko < 2; ++ko) {
                float4 fa = vp[ko * 8 + 2 * g + 0];
                float4 fb = vp[ko * 8 + 2 * g + 1];
                float f[8] = {fa.x, fa.y, fa.z, fa.w, fb.x, fb.y, fb.z, fb.w};
                #pragma unroll
                for (int i = 0; i < 8; ++i) {
                    uint  b  = __float_as_uint(f[i]);
                    float rr = f[i] - __uint_as_float(b & 0xffff0000u);   // exact
                    Ah[m][ko][i] = (short)(b >> 16);
                    Al[m][ko][i] = (short)(__float_as_uint(rr) >> 16);
                }
            }
        }

        const int tb = c * HROW + g * 8;               // B-frag base element in lWh/lWl

        // ---- pass 1: approx max per sample-slot (slot i = m*4+r -> sample m*16+4g+r) ----
        float m1[16];
        #pragma unroll
        for (int i = 0; i < 16; ++i) m1[i] = -FLT_MAX;

        #pragma unroll
        for (int t = 0; t < 16; ++t) {
            bf16x8 bh0 = *reinterpret_cast<const bf16x8*>(&lWh[tb + t * 16 * HROW]);
            bf16x8 bh1 = *reinterpret_cast<const bf16x8*>(&lWh[tb + t * 16 * HROW + 32]);
            bf16x8 bl0 = *reinterpret_cast<const bf16x8*>(&lWl[tb + t * 16 * HROW]);
            bf16x8 bl1 = *reinterpret_cast<const bf16x8*>(&lWl[tb + t * 16 * HROW + 32]);
            float w0c = lw0[t * 16 + c];
            #pragma unroll
            for (int m = 0; m < 4; ++m) {
                f32x4 a = {0.f, 0.f, 0.f, 0.f};
                a = MFMA(Al[m][0], bh0, a);
                a = MFMA(Ah[m][0], bl0, a);
                a = MFMA(Ah[m][0], bh0, a);
                a = MFMA(Al[m][1], bh1, a);
                a = MFMA(Ah[m][1], bl1, a);
                a = MFMA(Ah[m][1], bh1, a);
                #pragma unroll
                for (int r = 0; r < 4; ++r)
                    m1[m * 4 + r] = fmaxf(m1[m * 4 + r], a[r] + w0c);
            }
        }
        // reduce over the 16 column-lanes (same g) -> every lane has all 16 slot maxima
        #pragma unroll
        for (int d = 1; d < 16; d <<= 1) {
            #pragma unroll
            for (int i = 0; i < 16; ++i)
                m1[i] = fmaxf(m1[i], __shfl_xor(m1[i], d));
        }

        // ---- prefetch own valuations (hidden under pass-2 MFMAs; reused 3x below) ----
        const int s  = ms + lane;
        const int sc = (s < batch) ? s : (batch - 1);
        float v[ITEMS];
        {
            const float4* vp = reinterpret_cast<const float4*>(val + (size_t)sc * ITEMS);
            #pragma unroll
            for (int k = 0; k < 16; ++k) {
                float4 t4 = vp[k];
                v[4*k+0] = t4.x; v[4*k+1] = t4.y; v[4*k+2] = t4.z; v[4*k+3] = t4.w;
            }
        }

        // ---- pass 2: candidate bitmap (identical MFMA chain -> bit-identical accs) ----
        float thr[16];
        ushort cm[16];
        #pragma unroll
        for (int i = 0; i < 16; ++i) { thr[i] = m1[i] - BAND; cm[i] = 0; }

        #pragma unroll
        for (int t = 0; t < 16; ++t) {
            bf16x8 bh0 = *reinterpret_cast<const bf16x8*>(&lWh[tb + t * 16 * HROW]);
            bf16x8 bh1 = *reinterpret_cast<const bf16x8*>(&lWh[tb + t * 16 * HROW + 32]);
            bf16x8 bl0 = *reinterpret_cast<const bf16x8*>(&lWl[tb + t * 16 * HROW]);
            bf16x8 bl1 = *reinterpret_cast<const bf16x8*>(&lWl[tb + t * 16 * HROW + 32]);
            float w0c = lw0[t * 16 + c];
            #pragma unroll
            for (int m = 0; m < 4; ++m) {
                f32x4 a = {0.f, 0.f, 0.f, 0.f};
                a = MFMA(Al[m][0], bh0, a);
                a = MFMA(Ah[m][0], bl0, a);
                a = MFMA(Ah[m][0], bh0, a);
                a = MFMA(Al[m][1], bh1, a);
                a = MFMA(Ah[m][1], bl1, a);
                a = MFMA(Ah[m][1], bh1, a);
                #pragma unroll
                for (int r = 0; r < 4; ++r)
                    if (a[r] + w0c >= thr[m * 4 + r]) cm[m * 4 + r] |= (ushort)(1u << t);
            }
        }
        // scatter bitmap: row = sample-in-block, col = this lane's c (tile bits inside)
        #pragma unroll
        for (int i = 0; i < 16; ++i)
            cmask[(wave * 64 + (i >> 2) * 16 + 4 * g + (i & 3)) * 16 + c] = cm[i];

        // ---- owner thread: exact fp32 rescore of candidates only ----
        // Guarantee: candidate set contains the exact argmax; all non-candidates are
        // strictly below the exact winner. Tie-break = lowest j (jnp.argmax semantics).
        float hbest = -FLT_MAX;
        int   jbest = 0;
        {
            const uint* crow = reinterpret_cast<const uint*>(&cmask[tid * 16]);
            #pragma unroll
            for (int q = 0; q < 8; ++q) {
                uint e = crow[q];                       // cols 2q (lo16) / 2q+1 (hi16)
                while (e) {
                    int b = __ffs(e) - 1;
                    e &= e - 1;
                    int j = ((b & 15) << 4) + 2 * q + (b >> 4);   // j = t*16 + c
                    const float4* wr = reinterpret_cast<const float4*>(&lWf[j * WROW]);
                    float aa = 0.0f;                    // exact sequential fma chain
                    #pragma unroll
                    for (int k = 0; k < 16; ++k) {
                        float4 t4 = wr[k];
                        aa = fmaf(t4.x, v[4*k+0], aa); aa = fmaf(t4.y, v[4*k+1], aa);
                        aa = fmaf(t4.z, v[4*k+2], aa); aa = fmaf(t4.w, v[4*k+3], aa);
                    }
                    float h = aa + lw0[j];              // one separately-rounded +w0
                    if (h > hbest || (h == hbest && j < jbest)) { hbest = h; jbest = j; }
                }
            }
        }

        const bool pos = hbest > 0.0f;
        if (s < batch) {
            float p = 0.0f;
            const float4* wr = reinterpret_cast<const float4*>(&lWf[jbest * WROW]);
            #pragma unroll
            for (int k = 0; k < 16; ++k) {
                float4 t4 = wr[k];
                float ox = fminf(fmaxf(t4.x, 0.0f), 1.0f);
                float oy = fminf(fmaxf(t4.y, 0.0f), 1.0f);
                float oz = fminf(fmaxf(t4.z, 0.0f), 1.0f);
                float ow = fminf(fmaxf(t4.w, 0.0f), 1.0f);
                if (!pos) { ox = oy = oz = ow = 0.0f; }
                p = fmaf(ox, v[4*k+0], p);
                p = fmaf(oy, v[4*k+1], p);
                p = fmaf(oz, v[4*k+2], p);
                p = fmaf(ow, v[4*k+3], p);
            }
            p -= fmaxf(hbest, 0.0f);
            pay[s] = fmaxf(p, 0.0f);
        }

        // ---- wave-cooperative, fully-coalesced alloc store (unchanged pattern) ----
        stage[tid] = jbest | (pos ? 0x100 : 0);
        float4* allocF4 = reinterpret_cast<float4*>(alloc) + (size_t)ms * (ITEMS / 4);
        #pragma unroll
        for (int k = 0; k < 16; ++k) {
            int f = k * 64 + lane;
            int t = f >> 4, cc = f & 15;
            if (ms + t < batch) {
                int   pk = stage[wave * 64 + t];
                int   ti = pk & 0xff;
                bool  tp = (pk & 0x100) != 0;
                float4 wv = *reinterpret_cast<const float4*>(&lWf[ti * WROW + cc * 4]);
                float4 o;
                o.x = tp ? fminf(fmaxf(wv.x, 0.0f), 1.0f) : 0.0f;
                o.y = tp ? fminf(fmaxf(wv.y, 0.0f), 1.0f) : 0.0f;
                o.z = tp ? fminf(fmaxf(wv.z, 0.0f), 1.0f) : 0.0f;
                o.w = tp ? fminf(fmaxf(wv.w, 0.0f), 1.0f) : 0.0f;
                allocF4[f] = o;
            }
        }
    }
}

extern "C" void kernel_launch(void* const* d_in, const int* in_sizes, int n_in,
                              void* d_out, int out_size, void* d_ws, size_t ws_size,
                              hipStream_t stream) {
    const float* val = (const float*)d_in[0];   // [B,64]
    const float* W   = (const float*)d_in[1];   // [256,64]
    const float* w0  = (const float*)d_in[2];   // [256]
    float* out = (float*)d_out;
    int batch = in_sizes[0] / ITEMS;            // 1,000,000
    float* alloc = out;                         // [B,64]
    float* pay   = out + (size_t)batch * ITEMS; // [B]

    // Persistent grid: LDS (162,816 B) -> 1 block/CU; stage W once per CU.
    int nchunks = (batch + 63) / 64;
    int grid = (nchunks + (BLK / 64) - 1) / (BLK / 64);
    if (grid > 256) grid = 256;
    rochet_fwd<<<grid, BLK, 0, stream>>>(val, W, w0, alloc, pay, batch);
}

// Round 2
// 993.870 us; speedup vs baseline: 1.4414x; 1.4414x over previous
//
#include <hip/hip_runtime.h>
#include <cfloat>

#define ITEMS 64
#define HID   256
#define BLK   512               // 8 waves; each wave owns 64 samples per chunk
#define WROW  68                // fp32 W row stride (272 B, float4-aligned)
#define HROW  72                // bf16 W row stride (144 B, 16B-aligned)
#define BAND  0.016f            // 2*B ; worst-case |approx-exact| <= 3.9e-3, 2x margin

typedef __attribute__((ext_vector_type(8))) short bf16x8;   // 8 bf16 = 4 VGPRs
typedef __attribute__((ext_vector_type(4))) float f32x4;

#define MFMA(A,B,C) __builtin_amdgcn_mfma_f32_16x16x32_bf16((A),(B),(C),0,0,0)

__global__ __launch_bounds__(BLK, 2) void rochet_fwd(
    const float* __restrict__ val,   // [B, 64]
    const float* __restrict__ W,     // [256, 64]
    const float* __restrict__ w0,    // [256]
    float* __restrict__ alloc,       // [B, 64]
    float* __restrict__ pay,         // [B]
    int batch)
{
    // 36,864 + 36,864 + 69,632 + 16,384 + 1,024 + 2,048 = 162,816 B (<= 160 KiB)
    __shared__ __attribute__((aligned(16))) ushort lWh[HID * HROW];  // bf16 hi(W)
    __shared__ __attribute__((aligned(16))) ushort lWl[HID * HROW];  // bf16 lo(W)
    __shared__ __attribute__((aligned(16))) float  lWf[HID * WROW];  // exact fp32 W
    __shared__ __attribute__((aligned(16))) ushort cmask[BLK * 16];  // per-sample candidate bits
    __shared__ float lw0[HID];
    __shared__ int   stage[BLK];

    const int tid = threadIdx.x;

    // ---- Stage W: fp32 copy + truncation-split bf16 hi/lo; w0 ----
    {
        const int r  = tid >> 1;
        const int hh = (tid & 1) * 32;                 // half-row of 32 floats
        const float4* wg = reinterpret_cast<const float4*>(W + r * ITEMS + hh);
        float4* wf = reinterpret_cast<float4*>(&lWf[r * WROW + hh]);
        uint*   ph = reinterpret_cast<uint*>(&lWh[r * HROW + hh]);
        uint*   pl = reinterpret_cast<uint*>(&lWl[r * HROW + hh]);
        #pragma unroll
        for (int q = 0; q < 8; ++q) {
            float4 w4 = wg[q];
            wf[q] = w4;
            float f[4] = {w4.x, w4.y, w4.z, w4.w};
            #pragma unroll
            for (int p = 0; p < 2; ++p) {
                uint  b0 = __float_as_uint(f[2*p+0]);
                uint  b1 = __float_as_uint(f[2*p+1]);
                float r0 = f[2*p+0] - __uint_as_float(b0 & 0xffff0000u);  // exact
                float r1 = f[2*p+1] - __uint_as_float(b1 & 0xffff0000u);  // exact
                ph[2*q+p] = (b0 >> 16) | (b1 & 0xffff0000u);
                pl[2*q+p] = (__float_as_uint(r0) >> 16) | (__float_as_uint(r1) & 0xffff0000u);
            }
        }
        if (tid < HID) lw0[tid] = w0[tid];
    }
    __syncthreads();
    // Everything below is wave-local: no further block barriers.

    const int wave = tid >> 6, lane = tid & 63;
    const int c = lane & 15, g = lane >> 4;            // MFMA lane decomposition
    const int nchunks = (batch + 63) >> 6;             // 64-sample chunks
    const int nw = (gridDim.x * BLK) >> 6;             // total waves (persistent grid)

    for (int ch = blockIdx.x * (BLK >> 6) + wave; ch < nchunks; ch += nw) {
        const int ms = ch << 6;                        // this wave's first sample

        // ---- A fragments: val rows ms+m*16+c, k-block = 8*g (+32), bf16 hi/lo ----
        bf16x8 Ah[4][2], Al[4][2];
        #pragma unroll
        for (int m = 0; m < 4; ++m) {
            int srow = ms + m * 16 + c;
            if (srow >= batch) srow = batch - 1;       // safe duplicate; result unused
            const float4* vp = reinterpret_cast<const float4*>(val + (size_t)srow * ITEMS);
            #pragma unroll
            for (int ko = 0; ko < 2; ++ko) {
                float4 fa = vp[ko * 8 + 2 * g + 0];
                float4 fb = vp[ko * 8 + 2 * g + 1];
                float f[8] = {fa.x, fa.y, fa.z, fa.w, fb.x, fb.y, fb.z, fb.w};
                #pragma unroll
                for (int i = 0; i < 8; ++i) {
                    uint  b  = __float_as_uint(f[i]);
                    float rr = f[i] - __uint_as_float(b & 0xffff0000u);   // exact
                    Ah[m][ko][i] = (short)(b >> 16);
                    Al[m][ko][i] = (short)(__float_as_uint(rr) >> 16);
                }
            }
        }

        const int tb = c * HROW + g * 8;               // B-frag base element in lWh/lWl

        // ---- pass 1: approx max per sample-slot (slot i = m*4+r -> sample m*16+4g+r) ----
        float m1[16];
        #pragma unroll
        for (int i = 0; i < 16; ++i) m1[i] = -FLT_MAX;

        #pragma unroll
        for (int t = 0; t < 16; ++t) {
            bf16x8 bh0 = *reinterpret_cast<const bf16x8*>(&lWh[tb + t * 16 * HROW]);
            bf16x8 bh1 = *reinterpret_cast<const bf16x8*>(&lWh[tb + t * 16 * HROW + 32]);
            bf16x8 bl0 = *reinterpret_cast<const bf16x8*>(&lWl[tb + t * 16 * HROW]);
            bf16x8 bl1 = *reinterpret_cast<const bf16x8*>(&lWl[tb + t * 16 * HROW + 32]);
            float w0c = lw0[t * 16 + c];
            #pragma unroll
            for (int m = 0; m < 4; ++m) {
                f32x4 a = {0.f, 0.f, 0.f, 0.f};
                a = MFMA(Al[m][0], bh0, a);
                a = MFMA(Ah[m][0], bl0, a);
                a = MFMA(Ah[m][0], bh0, a);
                a = MFMA(Al[m][1], bh1, a);
                a = MFMA(Ah[m][1], bl1, a);
                a = MFMA(Ah[m][1], bh1, a);
                #pragma unroll
                for (int r = 0; r < 4; ++r)
                    m1[m * 4 + r] = fmaxf(m1[m * 4 + r], a[r] + w0c);
            }
        }
        // reduce over the 16 column-lanes (same g) -> every lane has all 16 slot maxima
        #pragma unroll
        for (int d = 1; d < 16; d <<= 1) {
            #pragma unroll
            for (int i = 0; i < 16; ++i)
                m1[i] = fmaxf(m1[i], __shfl_xor(m1[i], d));
        }

        // ---- pass 2: candidate bitmap (identical MFMA chain -> bit-identical accs) ----
        float thr[16];
        ushort cm[16];
        #pragma unroll
        for (int i = 0; i < 16; ++i) { thr[i] = m1[i] - BAND; cm[i] = 0; }

        #pragma unroll
        for (int t = 0; t < 16; ++t) {
            bf16x8 bh0 = *reinterpret_cast<const bf16x8*>(&lWh[tb + t * 16 * HROW]);
            bf16x8 bh1 = *reinterpret_cast<const bf16x8*>(&lWh[tb + t * 16 * HROW + 32]);
            bf16x8 bl0 = *reinterpret_cast<const bf16x8*>(&lWl[tb + t * 16 * HROW]);
            bf16x8 bl1 = *reinterpret_cast<const bf16x8*>(&lWl[tb + t * 16 * HROW + 32]);
            float w0c = lw0[t * 16 + c];
            #pragma unroll
            for (int m = 0; m < 4; ++m) {
                f32x4 a = {0.f, 0.f, 0.f, 0.f};
                a = MFMA(Al[m][0], bh0, a);
                a = MFMA(Ah[m][0], bl0, a);
                a = MFMA(Ah[m][0], bh0, a);
                a = MFMA(Al[m][1], bh1, a);
                a = MFMA(Ah[m][1], bl1, a);
                a = MFMA(Ah[m][1], bh1, a);
                #pragma unroll
                for (int r = 0; r < 4; ++r)
                    if (a[r] + w0c >= thr[m * 4 + r]) cm[m * 4 + r] |= (ushort)(1u << t);
            }
        }
        // scatter bitmap: row = sample-in-block, col = this lane's c (tile bits inside)
        #pragma unroll
        for (int i = 0; i < 16; ++i)
            cmask[(wave * 64 + (i >> 2) * 16 + 4 * g + (i & 3)) * 16 + c] = cm[i];
        // wave-local producer->consumer: drain LDS writes before cross-lane reads
        asm volatile("s_waitcnt lgkmcnt(0)" ::: "memory");

        // ---- owner thread: exact fp32 rescore of candidates only ----
        // val row is loaded on the fly (L1/L2-hot from phase A) -- no v[64] in regs,
        // which is what caused the round-1 scratch spill.
        const int s  = ms + lane;
        const int sc = (s < batch) ? s : (batch - 1);
        const float4* vg = reinterpret_cast<const float4*>(val + (size_t)sc * ITEMS);

        float hbest = -FLT_MAX;
        int   jbest = 0;
        {
            const uint* crow = reinterpret_cast<const uint*>(&cmask[tid * 16]);
            #pragma unroll
            for (int q = 0; q < 8; ++q) {
                uint e = crow[q];                       // cols 2q (lo16) / 2q+1 (hi16)
                while (e) {
                    int b = __ffs(e) - 1;
                    e &= e - 1;
                    int j = ((b & 15) << 4) + 2 * q + (b >> 4);   // j = t*16 + c
                    const float4* wr = reinterpret_cast<const float4*>(&lWf[j * WROW]);
                    float aa = 0.0f;                    // exact sequential fma chain
                    #pragma unroll
                    for (int k = 0; k < 16; ++k) {
                        float4 t4 = wr[k];
                        float4 vv = vg[k];
                        aa = fmaf(t4.x, vv.x, aa); aa = fmaf(t4.y, vv.y, aa);
                        aa = fmaf(t4.z, vv.z, aa); aa = fmaf(t4.w, vv.w, aa);
                    }
                    float h = aa + lw0[j];              // one separately-rounded +w0
                    if (h > hbest || (h == hbest && j < jbest)) { hbest = h; jbest = j; }
                }
            }
        }

        const bool pos = hbest > 0.0f;
        if (s < batch) {
            float p = 0.0f;
            const float4* wr = reinterpret_cast<const float4*>(&lWf[jbest * WROW]);
            #pragma unroll
            for (int k = 0; k < 16; ++k) {
                float4 t4 = wr[k];
                float4 vv = vg[k];                      // L1-hot (just read above)
                float ox = fminf(fmaxf(t4.x, 0.0f), 1.0f);
                float oy = fminf(fmaxf(t4.y, 0.0f), 1.0f);
                float oz = fminf(fmaxf(t4.z, 0.0f), 1.0f);
                float ow = fminf(fmaxf(t4.w, 0.0f), 1.0f);
                if (!pos) { ox = oy = oz = ow = 0.0f; }
                p = fmaf(ox, vv.x, p);
                p = fmaf(oy, vv.y, p);
                p = fmaf(oz, vv.z, p);
                p = fmaf(ow, vv.w, p);
            }
            p -= fmaxf(hbest, 0.0f);
            pay[s] = fmaxf(p, 0.0f);
        }

        // ---- wave-cooperative, fully-coalesced alloc store ----
        stage[tid] = jbest | (pos ? 0x100 : 0);
        asm volatile("s_waitcnt lgkmcnt(0)" ::: "memory");   // wave-local handoff
        float4* allocF4 = reinterpret_cast<float4*>(alloc) + (size_t)ms * (ITEMS / 4);
        #pragma unroll
        for (int k = 0; k < 16; ++k) {
            int f = k * 64 + lane;
            int t = f >> 4, cc = f & 15;
            if (ms + t < batch) {
                int   pk = stage[wave * 64 + t];
                int   ti = pk & 0xff;
                bool  tp = (pk & 0x100) != 0;
                float4 wv = *reinterpret_cast<const float4*>(&lWf[ti * WROW + cc * 4]);
                float4 o;
                o.x = tp ? fminf(fmaxf(wv.x, 0.0f), 1.0f) : 0.0f;
                o.y = tp ? fminf(fmaxf(wv.y, 0.0f), 1.0f) : 0.0f;
                o.z = tp ? fminf(fmaxf(wv.z, 0.0f), 1.0f) : 0.0f;
                o.w = tp ? fminf(fmaxf(wv.w, 0.0f), 1.0f) : 0.0f;
                allocF4[f] = o;
            }
        }
    }
}

extern "C" void kernel_launch(void* const* d_in, const int* in_sizes, int n_in,
                              void* d_out, int out_size, void* d_ws, size_t ws_size,
                              hipStream_t stream) {
    const float* val = (const float*)d_in[0];   // [B,64]
    const float* W   = (const float*)d_in[1];   // [256,64]
    const float* w0  = (const float*)d_in[2];   // [256]
    float* out = (float*)d_out;
    int batch = in_sizes[0] / ITEMS;            // 1,000,000
    float* alloc = out;                         // [B,64]
    float* pay   = out + (size_t)batch * ITEMS; // [B]

    // Persistent grid: LDS (162,816 B) -> 1 block/CU; stage W once per CU.
    int nchunks = (batch + 63) / 64;
    int grid = (nchunks + (BLK / 64) - 1) / (BLK / 64);
    if (grid > 256) grid = 256;
    rochet_fwd<<<grid, BLK, 0, stream>>>(val, W, w0, alloc, pay, batch);
}

// Round 4
// 523.885 us; speedup vs baseline: 2.7345x; 1.8971x over previous
//
#include <hip/hip_runtime.h>
#include <cfloat>

#define ITEMS 64
#define HID   256
#define BLK   512               // 8 waves; each wave owns CHUNK samples per iteration
#define WROW  68                // fp32 W row stride (272 B, float4-aligned)
#define HROW  72                // bf16 W row stride (144 B, 16B-aligned, 2-way-free banks)
#define BAND  0.016f            // 2*B ; worst-case |approx-exact| <= 3.9e-3, 2x margin
#define MT    2                 // M-tiles per wave-chunk (2 x 16 = 32 samples)
#define CHUNK 32

typedef __attribute__((ext_vector_type(8))) short bf16x8;   // 8 bf16 = 4 VGPRs
typedef __attribute__((ext_vector_type(4))) float f32x4;

#define MFMA(A,B,C) __builtin_amdgcn_mfma_f32_16x16x32_bf16((A),(B),(C),0,0,0)

__global__ __launch_bounds__(BLK, 2) void rochet_fwd(
    const float* __restrict__ val,   // [B, 64]
    const float* __restrict__ W,     // [256, 64]
    const float* __restrict__ w0,    // [256]
    float* __restrict__ alloc,       // [B, 64]
    float* __restrict__ pay,         // [B]
    int batch)
{
    // 36,864 + 36,864 + 69,632 + 8,192 + 1,024 + 1,024 = 153,600 B (<= 160 KiB)
    __shared__ __attribute__((aligned(16))) ushort lWh[HID * HROW];    // bf16 hi(W)
    __shared__ __attribute__((aligned(16))) ushort lWl[HID * HROW];    // bf16 lo(W)
    __shared__ __attribute__((aligned(16))) float  lWf[HID * WROW];    // exact fp32 W
    __shared__ __attribute__((aligned(16))) ushort cmask[(BLK/2) * 16];// candidate bits
    __shared__ float lw0[HID];
    __shared__ int   stage[BLK / 2];

    const int tid = threadIdx.x;

    // ---- Stage W: fp32 copy + truncation-split bf16 hi/lo; w0 ----
    {
        const int r  = tid >> 1;
        const int hh = (tid & 1) * 32;                 // half-row of 32 floats
        const float4* wg = reinterpret_cast<const float4*>(W + r * ITEMS + hh);
        float4* wf = reinterpret_cast<float4*>(&lWf[r * WROW + hh]);
        uint*   ph = reinterpret_cast<uint*>(&lWh[r * HROW + hh]);
        uint*   pl = reinterpret_cast<uint*>(&lWl[r * HROW + hh]);
        #pragma unroll
        for (int q = 0; q < 8; ++q) {
            float4 w4 = wg[q];
            wf[q] = w4;
            float f[4] = {w4.x, w4.y, w4.z, w4.w};
            #pragma unroll
            for (int p = 0; p < 2; ++p) {
                uint  b0 = __float_as_uint(f[2*p+0]);
                uint  b1 = __float_as_uint(f[2*p+1]);
                float r0 = f[2*p+0] - __uint_as_float(b0 & 0xffff0000u);  // exact
                float r1 = f[2*p+1] - __uint_as_float(b1 & 0xffff0000u);  // exact
                ph[2*q+p] = (b0 >> 16) | (b1 & 0xffff0000u);
                pl[2*q+p] = (__float_as_uint(r0) >> 16) | (__float_as_uint(r1) & 0xffff0000u);
            }
        }
        if (tid < HID) lw0[tid] = w0[tid];
    }
    __syncthreads();
    // Everything below is wave-local: no further block barriers.

    const int wave = tid >> 6, lane = tid & 63;
    const int c = lane & 15, g = lane >> 4;            // MFMA lane decomposition
    const int nchunks = (batch + CHUNK - 1) / CHUNK;
    const int nw = gridDim.x * (BLK / 64);             // total waves (persistent grid)

    for (int ch = blockIdx.x * (BLK / 64) + wave; ch < nchunks; ch += nw) {
        const int ms = ch * CHUNK;                     // this wave's first sample

        // ---- A fragments: val rows ms+m*16+c, k-elems 8*g..8*g+7 (+32), hi/lo ----
        bf16x8 Ah[MT][2], Al[MT][2];
        #pragma unroll
        for (int m = 0; m < MT; ++m) {
            int srow = ms + m * 16 + c;
            if (srow >= batch) srow = batch - 1;       // safe duplicate; result unused
            const float4* vp = reinterpret_cast<const float4*>(val + (size_t)srow * ITEMS);
            #pragma unroll
            for (int ko = 0; ko < 2; ++ko) {
                float4 fa = vp[ko * 8 + 2 * g + 0];
                float4 fb = vp[ko * 8 + 2 * g + 1];
                float f[8] = {fa.x, fa.y, fa.z, fa.w, fb.x, fb.y, fb.z, fb.w};
                #pragma unroll
                for (int i = 0; i < 8; ++i) {
                    uint  b  = __float_as_uint(f[i]);
                    float rr = f[i] - __uint_as_float(b & 0xffff0000u);   // exact
                    Ah[m][ko][i] = (short)(b >> 16);
                    Al[m][ko][i] = (short)(__float_as_uint(rr) >> 16);
                }
            }
        }

        const int tb = c * HROW + g * 8;               // B-frag base element in lWh/lWl

        // ---- pass 1: approx max per slot (slot i=m*4+r -> sample m*16+4g+r) ----
        float m1[MT * 4];
        #pragma unroll
        for (int i = 0; i < MT * 4; ++i) m1[i] = -FLT_MAX;

        #pragma unroll
        for (int t = 0; t < 16; ++t) {
            bf16x8 bh0 = *reinterpret_cast<const bf16x8*>(&lWh[tb + t * 16 * HROW]);
            bf16x8 bh1 = *reinterpret_cast<const bf16x8*>(&lWh[tb + t * 16 * HROW + 32]);
            bf16x8 bl0 = *reinterpret_cast<const bf16x8*>(&lWl[tb + t * 16 * HROW]);
            bf16x8 bl1 = *reinterpret_cast<const bf16x8*>(&lWl[tb + t * 16 * HROW + 32]);
            float w0c = lw0[t * 16 + c];
            #pragma unroll
            for (int m = 0; m < MT; ++m) {
                f32x4 a = {0.f, 0.f, 0.f, 0.f};
                a = MFMA(Al[m][0], bh0, a);
                a = MFMA(Ah[m][0], bl0, a);
                a = MFMA(Ah[m][0], bh0, a);
                a = MFMA(Al[m][1], bh1, a);
                a = MFMA(Ah[m][1], bl1, a);
                a = MFMA(Ah[m][1], bh1, a);
                #pragma unroll
                for (int r = 0; r < 4; ++r)
                    m1[m * 4 + r] = fmaxf(m1[m * 4 + r], a[r] + w0c);
            }
        }
        // reduce over the 16 column-lanes (same g) -> all lanes hold slot maxima
        #pragma unroll
        for (int d = 1; d < 16; d <<= 1) {
            #pragma unroll
            for (int i = 0; i < MT * 4; ++i)
                m1[i] = fmaxf(m1[i], __shfl_xor(m1[i], d));
        }
        #pragma unroll
        for (int i = 0; i < MT * 4; ++i) m1[i] -= BAND;   // threshold, in place

        // ---- pass 2: candidate bitmap (identical MFMA chain -> identical accs) ----
        uint cm[MT * 4];
        #pragma unroll
        for (int i = 0; i < MT * 4; ++i) cm[i] = 0;

        #pragma unroll
        for (int t = 0; t < 16; ++t) {
            bf16x8 bh0 = *reinterpret_cast<const bf16x8*>(&lWh[tb + t * 16 * HROW]);
            bf16x8 bh1 = *reinterpret_cast<const bf16x8*>(&lWh[tb + t * 16 * HROW + 32]);
            bf16x8 bl0 = *reinterpret_cast<const bf16x8*>(&lWl[tb + t * 16 * HROW]);
            bf16x8 bl1 = *reinterpret_cast<const bf16x8*>(&lWl[tb + t * 16 * HROW + 32]);
            float w0c = lw0[t * 16 + c];
            #pragma unroll
            for (int m = 0; m < MT; ++m) {
                f32x4 a = {0.f, 0.f, 0.f, 0.f};
                a = MFMA(Al[m][0], bh0, a);
                a = MFMA(Ah[m][0], bl0, a);
                a = MFMA(Ah[m][0], bh0, a);
                a = MFMA(Al[m][1], bh1, a);
                a = MFMA(Ah[m][1], bl1, a);
                a = MFMA(Ah[m][1], bh1, a);
                #pragma unroll
                for (int r = 0; r < 4; ++r)
                    if (a[r] + w0c >= m1[m * 4 + r]) cm[m * 4 + r] |= (1u << t);
            }
        }
        // scatter bitmap: row = sample-in-chunk, col = this lane's c
        #pragma unroll
        for (int i = 0; i < MT * 4; ++i)
            cmask[(wave * CHUNK + (i >> 2) * 16 + 4 * g + (i & 3)) * 16 + c] = (ushort)cm[i];
        asm volatile("s_waitcnt lgkmcnt(0)" ::: "memory");   // wave-local handoff

        // ---- owner lanes (lane < 32): exact fp32 rescore of candidates only ----
        const int s  = ms + lane;
        const int sc = (s < batch) ? s : (batch - 1);
        const float4* vg = reinterpret_cast<const float4*>(val + (size_t)sc * ITEMS);

        float hbest = -FLT_MAX;
        int   jbest = 0;
        if (lane < CHUNK) {
            const uint* crow = reinterpret_cast<const uint*>(&cmask[(wave * CHUNK + lane) * 16]);
            #pragma unroll
            for (int q = 0; q < 8; ++q) {
                uint e = crow[q];                       // cols 2q (lo16) / 2q+1 (hi16)
                while (e) {
                    int b = __ffs(e) - 1;
                    e &= e - 1;
                    int j = ((b & 15) << 4) + 2 * q + (b >> 4);   // j = t*16 + c
                    const float4* wr = reinterpret_cast<const float4*>(&lWf[j * WROW]);
                    float aa = 0.0f;                    // exact sequential fma chain
                    #pragma unroll
                    for (int k = 0; k < 16; ++k) {
                        float4 t4 = wr[k];
                        float4 vv = vg[k];
                        aa = fmaf(t4.x, vv.x, aa); aa = fmaf(t4.y, vv.y, aa);
                        aa = fmaf(t4.z, vv.z, aa); aa = fmaf(t4.w, vv.w, aa);
                    }
                    float h = aa + lw0[j];              // one separately-rounded +w0
                    if (h > hbest || (h == hbest && j < jbest)) { hbest = h; jbest = j; }
                }
            }
        }

        const bool pos = hbest > 0.0f;
        if (lane < CHUNK && s < batch) {
            float p = 0.0f;
            const float4* wr = reinterpret_cast<const float4*>(&lWf[jbest * WROW]);
            #pragma unroll
            for (int k = 0; k < 16; ++k) {
                float4 t4 = wr[k];
                float4 vv = vg[k];                      // L1-hot (just read above)
                float ox = fminf(fmaxf(t4.x, 0.0f), 1.0f);
                float oy = fminf(fmaxf(t4.y, 0.0f), 1.0f);
                float oz = fminf(fmaxf(t4.z, 0.0f), 1.0f);
                float ow = fminf(fmaxf(t4.w, 0.0f), 1.0f);
                if (!pos) { ox = oy = oz = ow = 0.0f; }
                p = fmaf(ox, vv.x, p);
                p = fmaf(oy, vv.y, p);
                p = fmaf(oz, vv.z, p);
                p = fmaf(ow, vv.w, p);
            }
            p -= fmaxf(hbest, 0.0f);
            pay[s] = fmaxf(p, 0.0f);
        }

        // ---- wave-cooperative, fully-coalesced alloc store ----
        if (lane < CHUNK) stage[wave * CHUNK + lane] = jbest | (pos ? 0x100 : 0);
        asm volatile("s_waitcnt lgkmcnt(0)" ::: "memory");   // wave-local handoff
        float4* allocF4 = reinterpret_cast<float4*>(alloc) + (size_t)ms * (ITEMS / 4);
        #pragma unroll
        for (int k = 0; k < 8; ++k) {
            int f = k * 64 + lane;                     // float4 index in 8 KB tile
            int t = f >> 4, cc = f & 15;
            if (ms + t < batch) {
                int   pk = stage[wave * CHUNK + t];
                int   ti = pk & 0xff;
                bool  tp = (pk & 0x100) != 0;
                float4 wv = *reinterpret_cast<const float4*>(&lWf[ti * WROW + cc * 4]);
                float4 o;
                o.x = tp ? fminf(fmaxf(wv.x, 0.0f), 1.0f) : 0.0f;
                o.y = tp ? fminf(fmaxf(wv.y, 0.0f), 1.0f) : 0.0f;
                o.z = tp ? fminf(fmaxf(wv.z, 0.0f), 1.0f) : 0.0f;
                o.w = tp ? fminf(fmaxf(wv.w, 0.0f), 1.0f) : 0.0f;
                allocF4[f] = o;
            }
        }
    }
}

extern "C" void kernel_launch(void* const* d_in, const int* in_sizes, int n_in,
                              void* d_out, int out_size, void* d_ws, size_t ws_size,
                              hipStream_t stream) {
    const float* val = (const float*)d_in[0];   // [B,64]
    const float* W   = (const float*)d_in[1];   // [256,64]
    const float* w0  = (const float*)d_in[2];   // [256]
    float* out = (float*)d_out;
    int batch = in_sizes[0] / ITEMS;            // 1,000,000
    float* alloc = out;                         // [B,64]
    float* pay   = out + (size_t)batch * ITEMS; // [B]

    // Persistent grid: LDS (153,600 B) -> 1 block/CU; stage W once per CU.
    int nchunks = (batch + CHUNK - 1) / CHUNK;
    int grid = (nchunks + (BLK / 64) - 1) / (BLK / 64);
    if (grid > 256) grid = 256;
    rochet_fwd<<<grid, BLK, 0, stream>>>(val, W, w0, alloc, pay, batch);
}